// Round 1
// baseline (1327.342 us; speedup 1.0000x reference)
//
#include <hip/hip_runtime.h>
#include <stdint.h>

#define B 64
#define H 384
#define W 512
#define NPX (H*W)            // 196608
#define TRIM_IDX 157286      // int(0.8 * 196608)

#define NB1 2048             // stage1/2 bins (11 bits)
#define NB3 1024             // stage3 bins (10 bits)

// ---- workspace layout (uint32 units) ----
#define HIST_OFF 0
#define HIST_U32 (2*B*NB1)               // 262144 u32 = 1 MB
#define ACC_OFF  (HIST_OFF + HIST_U32)
#define N_OFF    (ACC_OFF + 0)           // [B]  mask count (targ>0)
#define C2_OFF   (ACC_OFF + 64)          // [B]  count targ>shift_t
#define MS_OFF   (ACC_OFF + 128)         // [3][B] subsample mask counts
#define SS_OFF   (ACC_OFF + 320)         // [2][B] float abs-dev sums
#define TS_OFF   (ACC_OFF + 448)         // [B] float tmae sum
#define GS_OFF   (ACC_OFF + 512)         // [4][B] float grad sums
#define ACC_U32  768
#define ST_OFF   (ACC_OFF + ACC_U32)
#define K_OFF    (ST_OFF + 0)            // [2][B] remaining rank
#define PFX_OFF  (ST_OFF + 128)          // [2][B] selected bit prefix
#define SH_OFF   (ST_OFF + 256)          // [2][B] float shift (median)
#define RS_OFF   (ST_OFF + 384)          // [2][B] float reciprocal scale
#define THR_OFF  (ST_OFF + 512)          // [B] float trim threshold

__device__ __forceinline__ uint32_t fmap(float f) {
    uint32_t b = __float_as_uint(f);
    return (b & 0x80000000u) ? ~b : (b | 0x80000000u);
}
__device__ __forceinline__ float funmap(uint32_t u) {
    uint32_t b = (u & 0x80000000u) ? (u & 0x7fffffffu) : ~u;
    return __uint_as_float(b);
}

// ---------------- histogram passes ----------------
template <int STAGE>
__global__ void hist_kernel(const float* __restrict__ pred,
                            const float* __restrict__ targ,
                            uint32_t* __restrict__ ws) {
    constexpr int NB = (STAGE == 3) ? NB3 : NB1;
    __shared__ uint32_t lh[2 * NB];
    const int b = blockIdx.y;
    uint32_t* hist = ws + HIST_OFF;
    for (int i = threadIdx.x; i < 2 * NB; i += blockDim.x) lh[i] = 0;
    uint32_t pfxp = 0, pfxt = 0;
    if (STAGE > 1) { pfxp = ws[PFX_OFF + b]; pfxt = ws[PFX_OFF + B + b]; }
    __syncthreads();
    const float* pb = pred + (size_t)b * NPX;
    const float* tb = targ + (size_t)b * NPX;
    uint32_t nloc = 0;
    const int stride = gridDim.x * blockDim.x;
    for (int idx = blockIdx.x * blockDim.x + threadIdx.x; idx < NPX; idx += stride) {
        float tv = tb[idx];
        if (tv > 0.f) {
            nloc++;
            uint32_t up = fmap(pb[idx]);
            uint32_t ut = fmap(tv);
            if (STAGE == 1) {
                atomicAdd(&lh[up >> 21], 1u);
                atomicAdd(&lh[NB + (ut >> 21)], 1u);
            } else if (STAGE == 2) {
                if ((up >> 21) == pfxp) atomicAdd(&lh[(up >> 10) & 2047u], 1u);
                if ((ut >> 21) == pfxt) atomicAdd(&lh[NB + ((ut >> 10) & 2047u)], 1u);
            } else {
                if ((up >> 10) == pfxp) atomicAdd(&lh[up & 1023u], 1u);
                if ((ut >> 10) == pfxt) atomicAdd(&lh[NB + (ut & 1023u)], 1u);
            }
        }
    }
    __syncthreads();
    for (int i = threadIdx.x; i < 2 * NB; i += blockDim.x) {
        uint32_t v = lh[i];
        if (v) {
            int which = (i >= NB) ? 1 : 0;
            int bin = i - which * NB;
            atomicAdd(&hist[(size_t)(which * B + b) * NB1 + bin], v);
        }
    }
    if (STAGE == 1) {
        for (int off = 32; off; off >>= 1) nloc += __shfl_down(nloc, off, 64);
        if ((threadIdx.x & 63) == 0 && nloc) atomicAdd(ws + N_OFF + b, nloc);
    }
}

// ---------------- select within histogram ----------------
template <int STAGE>
__global__ void select_kernel(uint32_t* __restrict__ ws) {
    constexpr int NB = (STAGE == 3) ? NB3 : NB1;
    constexpr int CHUNK = NB / 256;
    const int b = blockIdx.x, which = blockIdx.y;
    const uint32_t* h = ws + HIST_OFF + (size_t)(which * B + b) * NB1;
    uint32_t* karr = ws + K_OFF + which * B;
    uint32_t* parr = ws + PFX_OFF + which * B;
    const uint32_t k = (STAGE == 1) ? ((ws[N_OFF + b] - 1u) >> 1) : karr[b];
    const int t = threadIdx.x;
    uint32_t mysum = 0;
    for (int i = 0; i < CHUNK; i++) mysum += h[t * CHUNK + i];
    __shared__ uint32_t s[256];
    s[t] = mysum;
    __syncthreads();
    for (int off = 1; off < 256; off <<= 1) {
        uint32_t add = (t >= off) ? s[t - off] : 0u;
        __syncthreads();
        s[t] += add;
        __syncthreads();
    }
    uint32_t incl = s[t];
    uint32_t excl = incl - mysum;
    if (k >= excl && k < incl) {
        uint32_t c = excl, bin = 0, newk = 0;
        for (int i = 0; i < CHUNK; i++) {
            uint32_t hv = h[t * CHUNK + i];
            if (k < c + hv) { bin = t * CHUNK + i; newk = k - c; break; }
            c += hv;
        }
        if (STAGE == 1)      { parr[b] = bin; karr[b] = newk; }
        else if (STAGE == 2) { parr[b] = (parr[b] << 11) | bin; karr[b] = newk; }
        else {
            uint32_t u = (parr[b] << 10) | bin;
            ((float*)(ws + SH_OFF))[which * B + b] = funmap(u);
        }
    }
}

// ---------------- abs-dev scale + count(targ > shift_t) ----------------
__global__ void scale_kernel(const float* __restrict__ pred,
                             const float* __restrict__ targ,
                             uint32_t* __restrict__ ws) {
    const int b = blockIdx.y;
    const float sp = ((const float*)(ws + SH_OFF))[b];
    const float st = ((const float*)(ws + SH_OFF))[B + b];
    const float* pb = pred + (size_t)b * NPX;
    const float* tb = targ + (size_t)b * NPX;
    float ap = 0.f, at = 0.f;
    uint32_t c2 = 0;
    const int stride = gridDim.x * blockDim.x;
    for (int idx = blockIdx.x * blockDim.x + threadIdx.x; idx < NPX; idx += stride) {
        float tv = tb[idx];
        if (tv > 0.f) {
            ap += fabsf(pb[idx] - sp);
            at += fabsf(tv - st);
        }
        if (tv > st) c2++;
    }
    for (int off = 32; off; off >>= 1) {
        ap += __shfl_down(ap, off, 64);
        at += __shfl_down(at, off, 64);
        c2 += __shfl_down(c2, off, 64);
    }
    if ((threadIdx.x & 63) == 0) {
        atomicAdd(((float*)(ws + SS_OFF)) + b, ap);
        atomicAdd(((float*)(ws + SS_OFF)) + B + b, at);
        if (c2) atomicAdd(ws + C2_OFF + b, c2);
    }
}

// ---------------- reciprocal scales + trim threshold ----------------
__global__ void thr_kernel(const float* __restrict__ pred,
                           const float* __restrict__ targ,
                           uint32_t* __restrict__ ws) {
    const int b = threadIdx.x;
    if (b >= B) return;
    float n = (float)ws[N_OFF + b];
    float scp = ((const float*)(ws + SS_OFF))[b] / n;
    float sct = ((const float*)(ws + SS_OFF))[B + b] / n;
    float rp = 1.f / scp, rt = 1.f / sct;
    ((float*)(ws + RS_OFF))[b] = rp;
    ((float*)(ws + RS_OFF))[B + b] = rt;
    uint32_t c2 = ws[C2_OFF + b];
    uint32_t mi = (uint32_t)(NPX - c2) + (uint32_t)TRIM_IDX;
    if (mi > (uint32_t)(NPX - 1)) mi = NPX - 1;
    const float sp = ((const float*)(ws + SH_OFF))[b];
    const float st = ((const float*)(ws + SH_OFF))[B + b];
    float p = pred[(size_t)b * NPX + mi];
    float t = targ[(size_t)b * NPX + mi];
    float pn = (p - sp) * rp, tn = (t - st) * rt;
    float thr = (tn > 0.f) ? fabsf(pn - tn) : 0.f;
    ((float*)(ws + THR_OFF))[b] = thr;
}

// ---------------- full-res: trimmed MAE sum + scale-0 gradients ----------------
__global__ void loss0_kernel(const float* __restrict__ pred,
                             const float* __restrict__ targ,
                             uint32_t* __restrict__ ws) {
    const int b = blockIdx.y;
    const float sp = ((const float*)(ws + SH_OFF))[b];
    const float st = ((const float*)(ws + SH_OFF))[B + b];
    const float rp = ((const float*)(ws + RS_OFF))[b];
    const float rt = ((const float*)(ws + RS_OFF))[B + b];
    const float thr = ((const float*)(ws + THR_OFF))[b];
    const float* pb = pred + (size_t)b * NPX;
    const float* tb = targ + (size_t)b * NPX;
    float tl = 0.f, gl = 0.f;
    const int stride = gridDim.x * blockDim.x;
    for (int idx = blockIdx.x * blockDim.x + threadIdx.x; idx < NPX; idx += stride) {
        float t = tb[idx];
        bool m = (t > st);
        if (m) {
            float p = pb[idx];
            float pn = (p - sp) * rp, tn = (t - st) * rt;
            float r = fabsf(pn - tn);
            if (r <= thr) tl += r;
            int j = idx & (W - 1);
            if (j) {
                float t2 = tb[idx - 1];
                if (t2 > st) gl += fabsf(pn - (pb[idx - 1] - sp) * rp);
            }
            if (idx >= W) {
                float t2 = tb[idx - W];
                if (t2 > st) gl += fabsf(pn - (pb[idx - W] - sp) * rp);
            }
        }
    }
    for (int off = 32; off; off >>= 1) {
        tl += __shfl_down(tl, off, 64);
        gl += __shfl_down(gl, off, 64);
    }
    if ((threadIdx.x & 63) == 0) {
        atomicAdd(((float*)(ws + TS_OFF)) + b, tl);
        atomicAdd(((float*)(ws + GS_OFF)) + b, gl);
    }
}

// ---------------- strided scales 1..3 (step 2,4,8) ----------------
__global__ void lossS_kernel(const float* __restrict__ pred,
                             const float* __restrict__ targ,
                             uint32_t* __restrict__ ws) {
    const int b = blockIdx.y;
    const int z = blockIdx.z;            // 0,1,2 -> step 2,4,8
    const int step = 2 << z;
    const int Ws = 256 >> z;             // W/step
    const int Ns = (H / step) * Ws;
    const float sp = ((const float*)(ws + SH_OFF))[b];
    const float st = ((const float*)(ws + SH_OFF))[B + b];
    const float rp = ((const float*)(ws + RS_OFF))[b];
    const float* pb = pred + (size_t)b * NPX;
    const float* tb = targ + (size_t)b * NPX;
    float gl = 0.f;
    uint32_t ml = 0;
    const int stride = gridDim.x * blockDim.x;
    for (int idx = blockIdx.x * blockDim.x + threadIdx.x; idx < Ns; idx += stride) {
        int i = idx >> (8 - z);
        int j = idx & (Ws - 1);
        int o = i * step * W + j * step;
        float t = tb[o];
        bool m = (t > st);
        if (m) {
            ml++;
            float pn = (pb[o] - sp) * rp;
            if (j) {
                float t2 = tb[o - step];
                if (t2 > st) gl += fabsf(pn - (pb[o - step] - sp) * rp);
            }
            if (i) {
                float t2 = tb[o - step * W];
                if (t2 > st) gl += fabsf(pn - (pb[o - step * W] - sp) * rp);
            }
        }
    }
    for (int off = 32; off; off >>= 1) {
        gl += __shfl_down(gl, off, 64);
        ml += __shfl_down(ml, off, 64);
    }
    if ((threadIdx.x & 63) == 0) {
        atomicAdd(((float*)(ws + GS_OFF)) + (1 + z) * B + b, gl);
        if (ml) atomicAdd(ws + MS_OFF + z * B + b, ml);
    }
}

// ---------------- finalize ----------------
__global__ void finalize_kernel(const uint32_t* __restrict__ ws, float* __restrict__ out) {
    const int b = threadIdx.x;
    float v = 0.f;
    if (b < B) {
        float c2 = (float)ws[C2_OFF + b];
        const float* tsum = (const float*)(ws + TS_OFF);
        const float* gsum = (const float*)(ws + GS_OFF);
        float tm = (c2 > 0.f) ? tsum[b] / (2.f * c2) : 0.f;
        float g = (c2 > 0.f) ? gsum[b] / c2 : 0.f;
        for (int z = 0; z < 3; z++) {
            float ms = (float)ws[MS_OFF + z * B + b];
            g += (ms > 0.f) ? gsum[(1 + z) * B + b] / ms : 0.f;
        }
        v = tm + 0.5f * g;
    }
    for (int off = 32; off; off >>= 1) v += __shfl_down(v, off, 64);
    if (b == 0) out[0] = v * (1.f / 64.f);
}

extern "C" void kernel_launch(void* const* d_in, const int* in_sizes, int n_in,
                              void* d_out, int out_size, void* d_ws, size_t ws_size,
                              hipStream_t stream) {
    const float* pred = (const float*)d_in[0];
    const float* targ = (const float*)d_in[1];
    float* out = (float*)d_out;
    uint32_t* ws = (uint32_t*)d_ws;

    // zero hist + accumulators (state region is write-before-read)
    hipMemsetAsync(ws, 0, (size_t)(HIST_U32 + ACC_U32) * 4, stream);

    dim3 hb(256), hg(8, B);
    hist_kernel<1><<<hg, hb, 0, stream>>>(pred, targ, ws);
    select_kernel<1><<<dim3(B, 2), 256, 0, stream>>>(ws);

    hipMemsetAsync(ws, 0, (size_t)HIST_U32 * 4, stream);
    hist_kernel<2><<<hg, hb, 0, stream>>>(pred, targ, ws);
    select_kernel<2><<<dim3(B, 2), 256, 0, stream>>>(ws);

    hipMemsetAsync(ws, 0, (size_t)HIST_U32 * 4, stream);
    hist_kernel<3><<<hg, hb, 0, stream>>>(pred, targ, ws);
    select_kernel<3><<<dim3(B, 2), 256, 0, stream>>>(ws);

    scale_kernel<<<dim3(8, B), 256, 0, stream>>>(pred, targ, ws);
    thr_kernel<<<1, 64, 0, stream>>>(pred, targ, ws);
    loss0_kernel<<<dim3(192, B), 256, 0, stream>>>(pred, targ, ws);
    lossS_kernel<<<dim3(192, B, 3), 256, 0, stream>>>(pred, targ, ws);
    finalize_kernel<<<1, 64, 0, stream>>>(ws, out);
}

// Round 2
// 718.265 us; speedup vs baseline: 1.8480x; 1.8480x over previous
//
#include <hip/hip_runtime.h>
#include <stdint.h>

#define B 64
#define H 384
#define W 512
#define NPX (H*W)            // 196608
#define TRIM_IDX 157286      // int(0.8 * 196608)

#define NB1 2048             // stage1/2 bins (11 bits)
#define NB3 1024             // stage3 bins (10 bits)

// ---- workspace layout (uint32 units) ----
#define HIST_OFF 0
#define HIST_U32 (2*B*NB1)               // 262144 u32 = 1 MB
#define ACC_OFF  (HIST_OFF + HIST_U32)
#define N_OFF    (ACC_OFF + 0)           // [B]  mask count (targ>0)
#define C2_OFF   (ACC_OFF + 64)          // [B]  count targ>shift_t
#define MS_OFF   (ACC_OFF + 128)         // [3][B] subsample mask counts
#define SS_OFF   (ACC_OFF + 320)         // [2][B] float abs-dev sums
#define TS_OFF   (ACC_OFF + 448)         // [B] float tmae sum
#define GS_OFF   (ACC_OFF + 512)         // [4][B] float grad sums
#define ACC_U32  768
#define ST_OFF   (ACC_OFF + ACC_U32)
#define K_OFF    (ST_OFF + 0)            // [2][B] remaining rank
#define PFX_OFF  (ST_OFF + 128)          // [2][B] selected bit prefix
#define SH_OFF   (ST_OFF + 256)          // [2][B] float shift (median)
#define RS_OFF   (ST_OFF + 384)          // [2][B] float reciprocal scale
#define THR_OFF  (ST_OFF + 512)          // [B] float trim threshold

__device__ __forceinline__ uint32_t fmap(float f) {
    uint32_t b = __float_as_uint(f);
    return (b & 0x80000000u) ? ~b : (b | 0x80000000u);
}
__device__ __forceinline__ float funmap(uint32_t u) {
    uint32_t b = (u & 0x80000000u) ? (u & 0x7fffffffu) : ~u;
    return __uint_as_float(b);
}

// ---------------- histogram passes ----------------
template <int STAGE>
__global__ void hist_kernel(const float* __restrict__ pred,
                            const float* __restrict__ targ,
                            uint32_t* __restrict__ ws) {
    constexpr int NB = (STAGE == 3) ? NB3 : NB1;
    __shared__ uint32_t lh[2 * NB];
    const int b = blockIdx.y;
    uint32_t* hist = ws + HIST_OFF;
    for (int i = threadIdx.x; i < 2 * NB; i += blockDim.x) lh[i] = 0;
    uint32_t pfxp = 0, pfxt = 0;
    if (STAGE > 1) { pfxp = ws[PFX_OFF + b]; pfxt = ws[PFX_OFF + B + b]; }
    __syncthreads();
    const float* pb = pred + (size_t)b * NPX;
    const float* tb = targ + (size_t)b * NPX;
    uint32_t nloc = 0;
    const int stride = gridDim.x * blockDim.x;
    for (int idx = blockIdx.x * blockDim.x + threadIdx.x; idx < NPX; idx += stride) {
        float tv = tb[idx];
        if (tv > 0.f) {
            nloc++;
            uint32_t up = fmap(pb[idx]);
            uint32_t ut = fmap(tv);
            if (STAGE == 1) {
                atomicAdd(&lh[up >> 21], 1u);
                atomicAdd(&lh[NB + (ut >> 21)], 1u);
            } else if (STAGE == 2) {
                if ((up >> 21) == pfxp) atomicAdd(&lh[(up >> 10) & 2047u], 1u);
                if ((ut >> 21) == pfxt) atomicAdd(&lh[NB + ((ut >> 10) & 2047u)], 1u);
            } else {
                if ((up >> 10) == pfxp) atomicAdd(&lh[up & 1023u], 1u);
                if ((ut >> 10) == pfxt) atomicAdd(&lh[NB + (ut & 1023u)], 1u);
            }
        }
    }
    __syncthreads();
    for (int i = threadIdx.x; i < 2 * NB; i += blockDim.x) {
        uint32_t v = lh[i];
        if (v) {
            int which = (i >= NB) ? 1 : 0;
            int bin = i - which * NB;
            atomicAdd(&hist[(size_t)(which * B + b) * NB1 + bin], v);
        }
    }
    if (STAGE == 1) {
        for (int off = 32; off; off >>= 1) nloc += __shfl_down(nloc, off, 64);
        if ((threadIdx.x & 63) == 0 && nloc) atomicAdd(ws + N_OFF + b, nloc);
    }
}

// ---------------- select within histogram ----------------
template <int STAGE>
__global__ void select_kernel(uint32_t* __restrict__ ws) {
    constexpr int NB = (STAGE == 3) ? NB3 : NB1;
    constexpr int CHUNK = NB / 256;
    const int b = blockIdx.x, which = blockIdx.y;
    const uint32_t* h = ws + HIST_OFF + (size_t)(which * B + b) * NB1;
    uint32_t* karr = ws + K_OFF + which * B;
    uint32_t* parr = ws + PFX_OFF + which * B;
    const uint32_t k = (STAGE == 1) ? ((ws[N_OFF + b] - 1u) >> 1) : karr[b];
    const int t = threadIdx.x;
    uint32_t mysum = 0;
    for (int i = 0; i < CHUNK; i++) mysum += h[t * CHUNK + i];
    __shared__ uint32_t s[256];
    s[t] = mysum;
    __syncthreads();
    for (int off = 1; off < 256; off <<= 1) {
        uint32_t add = (t >= off) ? s[t - off] : 0u;
        __syncthreads();
        s[t] += add;
        __syncthreads();
    }
    uint32_t incl = s[t];
    uint32_t excl = incl - mysum;
    if (k >= excl && k < incl) {
        uint32_t c = excl, bin = 0, newk = 0;
        for (int i = 0; i < CHUNK; i++) {
            uint32_t hv = h[t * CHUNK + i];
            if (k < c + hv) { bin = t * CHUNK + i; newk = k - c; break; }
            c += hv;
        }
        if (STAGE == 1)      { parr[b] = bin; karr[b] = newk; }
        else if (STAGE == 2) { parr[b] = (parr[b] << 11) | bin; karr[b] = newk; }
        else {
            uint32_t u = (parr[b] << 10) | bin;
            ((float*)(ws + SH_OFF))[which * B + b] = funmap(u);
        }
    }
}

// ---------------- abs-dev scale + count(targ > shift_t) ----------------
__global__ void scale_kernel(const float* __restrict__ pred,
                             const float* __restrict__ targ,
                             uint32_t* __restrict__ ws) {
    const int b = blockIdx.y;
    const float sp = ((const float*)(ws + SH_OFF))[b];
    const float st = ((const float*)(ws + SH_OFF))[B + b];
    const float* pb = pred + (size_t)b * NPX;
    const float* tb = targ + (size_t)b * NPX;
    float ap = 0.f, at = 0.f;
    uint32_t c2 = 0;
    const int stride = gridDim.x * blockDim.x;
    for (int idx = blockIdx.x * blockDim.x + threadIdx.x; idx < NPX; idx += stride) {
        float tv = tb[idx];
        if (tv > 0.f) {
            ap += fabsf(pb[idx] - sp);
            at += fabsf(tv - st);
        }
        if (tv > st) c2++;
    }
    for (int off = 32; off; off >>= 1) {
        ap += __shfl_down(ap, off, 64);
        at += __shfl_down(at, off, 64);
        c2 += __shfl_down(c2, off, 64);
    }
    if ((threadIdx.x & 63) == 0) {
        atomicAdd(((float*)(ws + SS_OFF)) + b, ap);
        atomicAdd(((float*)(ws + SS_OFF)) + B + b, at);
        if (c2) atomicAdd(ws + C2_OFF + b, c2);
    }
}

// ---------------- reciprocal scales + trim threshold ----------------
__global__ void thr_kernel(const float* __restrict__ pred,
                           const float* __restrict__ targ,
                           uint32_t* __restrict__ ws) {
    const int b = threadIdx.x;
    if (b >= B) return;
    float n = (float)ws[N_OFF + b];
    float scp = ((const float*)(ws + SS_OFF))[b] / n;
    float sct = ((const float*)(ws + SS_OFF))[B + b] / n;
    float rp = 1.f / scp, rt = 1.f / sct;
    ((float*)(ws + RS_OFF))[b] = rp;
    ((float*)(ws + RS_OFF))[B + b] = rt;
    uint32_t c2 = ws[C2_OFF + b];
    uint32_t mi = (uint32_t)(NPX - c2) + (uint32_t)TRIM_IDX;
    if (mi > (uint32_t)(NPX - 1)) mi = NPX - 1;
    const float sp = ((const float*)(ws + SH_OFF))[b];
    const float st = ((const float*)(ws + SH_OFF))[B + b];
    float p = pred[(size_t)b * NPX + mi];
    float t = targ[(size_t)b * NPX + mi];
    float pn = (p - sp) * rp, tn = (t - st) * rt;
    float thr = (tn > 0.f) ? fabsf(pn - tn) : 0.f;
    ((float*)(ws + THR_OFF))[b] = thr;
}

// ---------------- fused loss: trimmed MAE + all 4 gradient scales ----------------
// Coalesced full-res sweep; strided-scale pixels are a subset, their left/up
// neighbors are L1/L2-resident because the same pass streams the whole image.
__global__ void loss_fused_kernel(const float* __restrict__ pred,
                                  const float* __restrict__ targ,
                                  uint32_t* __restrict__ ws) {
    const int b = blockIdx.y;
    const float sp = ((const float*)(ws + SH_OFF))[b];
    const float st = ((const float*)(ws + SH_OFF))[B + b];
    const float rp = ((const float*)(ws + RS_OFF))[b];
    const float rt = ((const float*)(ws + RS_OFF))[B + b];
    const float thr = ((const float*)(ws + THR_OFF))[b];
    const float* pb = pred + (size_t)b * NPX;
    const float* tb = targ + (size_t)b * NPX;
    float tl = 0.f, gl0 = 0.f, gl1 = 0.f, gl2 = 0.f, gl3 = 0.f;
    uint32_t m1 = 0, m2 = 0, m3 = 0;
    const int stride = gridDim.x * blockDim.x;
    for (int idx = blockIdx.x * blockDim.x + threadIdx.x; idx < NPX; idx += stride) {
        float t = tb[idx];
        if (t > st) {
            float p = pb[idx];
            float pn = (p - sp) * rp, tn = (t - st) * rt;
            float r = fabsf(pn - tn);
            if (r <= thr) tl += r;
            const int i = idx >> 9;          // row
            const int j = idx & (W - 1);     // col
            if (j)      { if (tb[idx - 1] > st)     gl0 += fabsf(pn - (pb[idx - 1] - sp) * rp); }
            if (i)      { if (tb[idx - W] > st)     gl0 += fabsf(pn - (pb[idx - W] - sp) * rp); }
            if (!(idx & ((1 << 9) | 1))) {          // i,j even -> scale 1 (step 2)
                m1++;
                if (j) { if (tb[idx - 2] > st)      gl1 += fabsf(pn - (pb[idx - 2] - sp) * rp); }
                if (i) { if (tb[idx - 2*W] > st)    gl1 += fabsf(pn - (pb[idx - 2*W] - sp) * rp); }
                if (!(idx & ((3 << 9) | 3))) {      // multiples of 4 -> scale 2
                    m2++;
                    if (j) { if (tb[idx - 4] > st)   gl2 += fabsf(pn - (pb[idx - 4] - sp) * rp); }
                    if (i) { if (tb[idx - 4*W] > st) gl2 += fabsf(pn - (pb[idx - 4*W] - sp) * rp); }
                    if (!(idx & ((7 << 9) | 7))) {  // multiples of 8 -> scale 3
                        m3++;
                        if (j) { if (tb[idx - 8] > st)   gl3 += fabsf(pn - (pb[idx - 8] - sp) * rp); }
                        if (i) { if (tb[idx - 8*W] > st) gl3 += fabsf(pn - (pb[idx - 8*W] - sp) * rp); }
                    }
                }
            }
        }
    }
    for (int off = 32; off; off >>= 1) {
        tl  += __shfl_down(tl, off, 64);
        gl0 += __shfl_down(gl0, off, 64);
        gl1 += __shfl_down(gl1, off, 64);
        gl2 += __shfl_down(gl2, off, 64);
        gl3 += __shfl_down(gl3, off, 64);
        m1  += __shfl_down(m1, off, 64);
        m2  += __shfl_down(m2, off, 64);
        m3  += __shfl_down(m3, off, 64);
    }
    if ((threadIdx.x & 63) == 0) {
        float* gs = (float*)(ws + GS_OFF);
        atomicAdd(((float*)(ws + TS_OFF)) + b, tl);
        atomicAdd(gs + b, gl0);
        atomicAdd(gs + B + b, gl1);
        atomicAdd(gs + 2 * B + b, gl2);
        atomicAdd(gs + 3 * B + b, gl3);
        if (m1) atomicAdd(ws + MS_OFF + b, m1);
        if (m2) atomicAdd(ws + MS_OFF + B + b, m2);
        if (m3) atomicAdd(ws + MS_OFF + 2 * B + b, m3);
    }
}

// ---------------- finalize ----------------
__global__ void finalize_kernel(const uint32_t* __restrict__ ws, float* __restrict__ out) {
    const int b = threadIdx.x;
    float v = 0.f;
    if (b < B) {
        float c2 = (float)ws[C2_OFF + b];
        const float* tsum = (const float*)(ws + TS_OFF);
        const float* gsum = (const float*)(ws + GS_OFF);
        float tm = (c2 > 0.f) ? tsum[b] / (2.f * c2) : 0.f;
        float g = (c2 > 0.f) ? gsum[b] / c2 : 0.f;
        for (int z = 0; z < 3; z++) {
            float ms = (float)ws[MS_OFF + z * B + b];
            g += (ms > 0.f) ? gsum[(1 + z) * B + b] / ms : 0.f;
        }
        v = tm + 0.5f * g;
    }
    for (int off = 32; off; off >>= 1) v += __shfl_down(v, off, 64);
    if (b == 0) out[0] = v * (1.f / 64.f);
}

extern "C" void kernel_launch(void* const* d_in, const int* in_sizes, int n_in,
                              void* d_out, int out_size, void* d_ws, size_t ws_size,
                              hipStream_t stream) {
    const float* pred = (const float*)d_in[0];
    const float* targ = (const float*)d_in[1];
    float* out = (float*)d_out;
    uint32_t* ws = (uint32_t*)d_ws;

    // zero hist + accumulators (state region is write-before-read)
    hipMemsetAsync(ws, 0, (size_t)(HIST_U32 + ACC_U32) * 4, stream);

    dim3 hb(256), hg(8, B);
    hist_kernel<1><<<hg, hb, 0, stream>>>(pred, targ, ws);
    select_kernel<1><<<dim3(B, 2), 256, 0, stream>>>(ws);

    hipMemsetAsync(ws, 0, (size_t)HIST_U32 * 4, stream);
    hist_kernel<2><<<hg, hb, 0, stream>>>(pred, targ, ws);
    select_kernel<2><<<dim3(B, 2), 256, 0, stream>>>(ws);

    hipMemsetAsync(ws, 0, (size_t)HIST_U32 * 4, stream);
    hist_kernel<3><<<hg, hb, 0, stream>>>(pred, targ, ws);
    select_kernel<3><<<dim3(B, 2), 256, 0, stream>>>(ws);

    scale_kernel<<<dim3(8, B), 256, 0, stream>>>(pred, targ, ws);
    thr_kernel<<<1, 64, 0, stream>>>(pred, targ, ws);
    loss_fused_kernel<<<dim3(192, B), 256, 0, stream>>>(pred, targ, ws);
    finalize_kernel<<<1, 64, 0, stream>>>(ws, out);
}

// Round 3
// 333.746 us; speedup vs baseline: 3.9771x; 2.1521x over previous
//
#include <hip/hip_runtime.h>
#include <stdint.h>

#define B 64
#define H 384
#define W 512
#define NPX (H*W)            // 196608
#define TRIM_IDX 157286      // int(0.8 * 196608)

#define NB1 2048             // stage1/2 bins (11 bits)
#define NB3 1024             // stage3 bins (10 bits)

// ---- workspace layout (uint32 units) ----
#define HIST_OFF 0
#define HIST_U32 (2*B*NB1)               // 262144 u32 = 1 MB
#define ACC_OFF  (HIST_OFF + HIST_U32)
#define N_OFF    (ACC_OFF + 0)           // [B]  u32 mask count (targ>0)
#define MS_OFF   (ACC_OFF + 64)          // [3][B] u32 subsample mask counts
#define TS_OFF   (ACC_OFF + 256)         // [B]  f32 tmae sum
#define GS_OFF   (ACC_OFF + 320)         // [4][B] f32 grad sums
#define TSUM_OFF (ACC_OFF + 576)         // [2][B] f32 total masked value sum
#define SB_OFF   (ACC_OFF + 704)         // [2][B] f32 sum of masked values < med
#define ZERO_U32 (HIST_U32 + 832)        // zero [0, ZERO_U32) at launch
// persistent (written before read each launch, not zeroed)
#define K_OFF    (ACC_OFF + 832)         // [2][B] u32 remaining rank
#define PFX_OFF  (ACC_OFF + 960)         // [2][B] u32 selected bit prefix
#define EQ_OFF   (ACC_OFF + 1088)        // [2][B] u32 count equal to median
#define SH_OFF   (ACC_OFF + 1216)        // [2][B] f32 median (shift)
#define RS_OFF   (ACC_OFF + 1344)        // [2][B] f32 reciprocal scale
#define THR_OFF  (ACC_OFF + 1472)        // [B]  f32 trim threshold
#define C2_OFF   (ACC_OFF + 1536)        // [B]  u32 count targ>shift_t

__device__ __forceinline__ uint32_t fmap(float f) {
    uint32_t b = __float_as_uint(f);
    return (b & 0x80000000u) ? ~b : (b | 0x80000000u);
}
__device__ __forceinline__ float funmap(uint32_t u) {
    uint32_t b = (u & 0x80000000u) ? (u & 0x7fffffffu) : ~u;
    return __uint_as_float(b);
}

// ---------------- stage 1: 11-bit histogram + n + total sums ----------------
__global__ void hist1_kernel(const float* __restrict__ pred,
                             const float* __restrict__ targ,
                             uint32_t* __restrict__ ws) {
    __shared__ uint32_t lh[2 * NB1];
    const int b = blockIdx.y;
    for (int i = threadIdx.x; i < 2 * NB1; i += blockDim.x) lh[i] = 0;
    __syncthreads();
    const float4* pb = (const float4*)(pred + (size_t)b * NPX);
    const float4* tb = (const float4*)(targ + (size_t)b * NPX);
    uint32_t nloc = 0;
    float sump = 0.f, sumt = 0.f;
    const int stride = gridDim.x * blockDim.x;
    for (int q = blockIdx.x * blockDim.x + threadIdx.x; q < NPX / 4; q += stride) {
        float4 tv = tb[q], pv = pb[q];
        float tA[4] = {tv.x, tv.y, tv.z, tv.w};
        float pA[4] = {pv.x, pv.y, pv.z, pv.w};
        #pragma unroll
        for (int k = 0; k < 4; k++) {
            float t = tA[k];
            if (t > 0.f) {
                float p = pA[k];
                nloc++; sumt += t; sump += p;
                atomicAdd(&lh[fmap(p) >> 21], 1u);
                atomicAdd(&lh[NB1 + (fmap(t) >> 21)], 1u);
            }
        }
    }
    __syncthreads();
    uint32_t* hist = ws + HIST_OFF;
    for (int i = threadIdx.x; i < 2 * NB1; i += blockDim.x) {
        uint32_t v = lh[i];
        if (v) {
            int which = i >> 11, bin = i & (NB1 - 1);
            atomicAdd(&hist[(size_t)(which * B + b) * NB1 + bin], v);
        }
    }
    for (int off = 32; off; off >>= 1) {
        nloc += __shfl_down(nloc, off, 64);
        sump += __shfl_down(sump, off, 64);
        sumt += __shfl_down(sumt, off, 64);
    }
    if ((threadIdx.x & 63) == 0) {
        if (nloc) atomicAdd(ws + N_OFF + b, nloc);
        atomicAdd(((float*)(ws + TSUM_OFF)) + b, sump);
        atomicAdd(((float*)(ws + TSUM_OFF)) + B + b, sumt);
    }
}

// ---------------- stage 2: mid-11-bit histogram + sum-below-stage1-bin ----------------
__global__ void hist2_kernel(const float* __restrict__ pred,
                             const float* __restrict__ targ,
                             uint32_t* __restrict__ ws) {
    __shared__ uint32_t lh[2 * NB1];
    const int b = blockIdx.y;
    for (int i = threadIdx.x; i < 2 * NB1; i += blockDim.x) lh[i] = 0;
    const uint32_t pfxp = ws[PFX_OFF + b];
    const uint32_t pfxt = ws[PFX_OFF + B + b];
    __syncthreads();
    const float4* pb = (const float4*)(pred + (size_t)b * NPX);
    const float4* tb = (const float4*)(targ + (size_t)b * NPX);
    float sbp = 0.f, sbt = 0.f;
    const int stride = gridDim.x * blockDim.x;
    for (int q = blockIdx.x * blockDim.x + threadIdx.x; q < NPX / 4; q += stride) {
        float4 tv = tb[q], pv = pb[q];
        float tA[4] = {tv.x, tv.y, tv.z, tv.w};
        float pA[4] = {pv.x, pv.y, pv.z, pv.w};
        #pragma unroll
        for (int k = 0; k < 4; k++) {
            float t = tA[k];
            if (t > 0.f) {
                float p = pA[k];
                uint32_t up = fmap(p), u1 = up >> 21;
                if (u1 < pfxp) sbp += p;
                else if (u1 == pfxp) atomicAdd(&lh[(up >> 10) & 2047u], 1u);
                uint32_t ut = fmap(t), v1 = ut >> 21;
                if (v1 < pfxt) sbt += t;
                else if (v1 == pfxt) atomicAdd(&lh[NB1 + ((ut >> 10) & 2047u)], 1u);
            }
        }
    }
    __syncthreads();
    uint32_t* hist = ws + HIST_OFF;
    for (int i = threadIdx.x; i < 2 * NB1; i += blockDim.x) {
        uint32_t v = lh[i];
        if (v) {
            int which = i >> 11, bin = i & (NB1 - 1);
            atomicAdd(&hist[(size_t)(which * B + b) * NB1 + bin], v);
        }
    }
    for (int off = 32; off; off >>= 1) {
        sbp += __shfl_down(sbp, off, 64);
        sbt += __shfl_down(sbt, off, 64);
    }
    if ((threadIdx.x & 63) == 0) {
        atomicAdd(((float*)(ws + SB_OFF)) + b, sbp);
        atomicAdd(((float*)(ws + SB_OFF)) + B + b, sbt);
    }
}

// ---------------- stage 3: low-10-bit hist + per-bin value sums + sum-below ----------------
__global__ void hist3_kernel(const float* __restrict__ pred,
                             const float* __restrict__ targ,
                             uint32_t* __restrict__ ws) {
    __shared__ uint32_t lc[2 * NB3];
    __shared__ float    lsm[2 * NB3];
    const int b = blockIdx.y;
    for (int i = threadIdx.x; i < 2 * NB3; i += blockDim.x) { lc[i] = 0; lsm[i] = 0.f; }
    const uint32_t pfx2p = ws[PFX_OFF + b];       // 22-bit
    const uint32_t pfx2t = ws[PFX_OFF + B + b];
    const uint32_t pfx1p = pfx2p >> 11;
    const uint32_t pfx1t = pfx2t >> 11;
    __syncthreads();
    const float4* pb = (const float4*)(pred + (size_t)b * NPX);
    const float4* tb = (const float4*)(targ + (size_t)b * NPX);
    float sbp = 0.f, sbt = 0.f;
    const int stride = gridDim.x * blockDim.x;
    for (int q = blockIdx.x * blockDim.x + threadIdx.x; q < NPX / 4; q += stride) {
        float4 tv = tb[q], pv = pb[q];
        float tA[4] = {tv.x, tv.y, tv.z, tv.w};
        float pA[4] = {pv.x, pv.y, pv.z, pv.w};
        #pragma unroll
        for (int k = 0; k < 4; k++) {
            float t = tA[k];
            if (t > 0.f) {
                float p = pA[k];
                uint32_t up = fmap(p), u21 = up >> 10;
                if ((u21 >> 11) == pfx1p) {
                    if (u21 < pfx2p) sbp += p;
                    else if (u21 == pfx2p) {
                        uint32_t bin = up & 1023u;
                        atomicAdd(&lc[bin], 1u);
                        atomicAdd(&lsm[bin], p);
                    }
                }
                uint32_t ut = fmap(t), v21 = ut >> 10;
                if ((v21 >> 11) == pfx1t) {
                    if (v21 < pfx2t) sbt += t;
                    else if (v21 == pfx2t) {
                        uint32_t bin = ut & 1023u;
                        atomicAdd(&lc[NB3 + bin], 1u);
                        atomicAdd(&lsm[NB3 + bin], t);
                    }
                }
            }
        }
    }
    __syncthreads();
    uint32_t* hist = ws + HIST_OFF;
    for (int i = threadIdx.x; i < 2 * NB3; i += blockDim.x) {
        uint32_t v = lc[i];
        if (v) {
            int which = i >> 10, bin = i & (NB3 - 1);
            uint32_t* slot = &hist[(size_t)(which * B + b) * NB1];
            atomicAdd(&slot[bin], v);
            atomicAdd((float*)&slot[NB3 + bin], lsm[i]);
        }
    }
    for (int off = 32; off; off >>= 1) {
        sbp += __shfl_down(sbp, off, 64);
        sbt += __shfl_down(sbt, off, 64);
    }
    if ((threadIdx.x & 63) == 0) {
        atomicAdd(((float*)(ws + SB_OFF)) + b, sbp);
        atomicAdd(((float*)(ws + SB_OFF)) + B + b, sbt);
    }
}

// ---------------- select stages 1/2 (counts only, 2048 bins) ----------------
template <int STAGE>
__global__ void select_kernel(uint32_t* __restrict__ ws) {
    const int b = blockIdx.x, which = blockIdx.y;
    const uint32_t* h = ws + HIST_OFF + (size_t)(which * B + b) * NB1;
    uint32_t* karr = ws + K_OFF + which * B;
    uint32_t* parr = ws + PFX_OFF + which * B;
    const uint32_t k = (STAGE == 1) ? ((ws[N_OFF + b] - 1u) >> 1) : karr[b];
    const int t = threadIdx.x;
    uint32_t mysum = 0;
    #pragma unroll
    for (int i = 0; i < 8; i++) mysum += h[t * 8 + i];
    __shared__ uint32_t s[256];
    s[t] = mysum;
    __syncthreads();
    for (int off = 1; off < 256; off <<= 1) {
        uint32_t add = (t >= off) ? s[t - off] : 0u;
        __syncthreads();
        s[t] += add;
        __syncthreads();
    }
    uint32_t incl = s[t], excl = incl - mysum;
    if (k >= excl && k < incl) {
        uint32_t c = excl, bin = 0, newk = 0;
        for (int i = 0; i < 8; i++) {
            uint32_t hv = h[t * 8 + i];
            if (k < c + hv) { bin = t * 8 + i; newk = k - c; break; }
            c += hv;
        }
        if (STAGE == 1) { parr[b] = bin; karr[b] = newk; }
        else            { parr[b] = (parr[b] << 11) | bin; karr[b] = newk; }
    }
}

// ---------------- select stage 3 (counts + value-sum prefix) ----------------
__global__ void select3_kernel(uint32_t* __restrict__ ws) {
    const int b = blockIdx.x, which = blockIdx.y;
    const uint32_t* h = ws + HIST_OFF + (size_t)(which * B + b) * NB1;
    const float* hs = (const float*)(h + NB3);
    const uint32_t k = ws[K_OFF + which * B + b];
    const int t = threadIdx.x;
    uint32_t mysum = 0; float myfs = 0.f;
    #pragma unroll
    for (int i = 0; i < 4; i++) { mysum += h[t * 4 + i]; myfs += hs[t * 4 + i]; }
    __shared__ uint32_t s[256];
    __shared__ float sf[256];
    s[t] = mysum; sf[t] = myfs;
    __syncthreads();
    for (int off = 1; off < 256; off <<= 1) {
        uint32_t add = (t >= off) ? s[t - off] : 0u;
        float addf = (t >= off) ? sf[t - off] : 0.f;
        __syncthreads();
        s[t] += add; sf[t] += addf;
        __syncthreads();
    }
    uint32_t incl = s[t], excl = incl - mysum;
    float fexcl = sf[t] - myfs;
    if (k >= excl && k < incl) {
        uint32_t c = excl, bin = 0, newk = 0, e = 0;
        float fs = fexcl;
        for (int i = 0; i < 4; i++) {
            uint32_t hv = h[t * 4 + i];
            if (k < c + hv) { bin = t * 4 + i; newk = k - c; e = hv; break; }
            c += hv;
            fs += hs[t * 4 + i];
        }
        uint32_t u = (ws[PFX_OFF + which * B + b] << 10) | bin;
        ((float*)(ws + SH_OFF))[which * B + b] = funmap(u);
        ws[K_OFF + which * B + b] = newk;
        ws[EQ_OFF + which * B + b] = e;
        ((float*)(ws + SB_OFF))[which * B + b] += fs;   // below-median sum within prefix group
    }
}

// ---------------- params: scales from sum decomposition, c2, trim threshold ----------------
__global__ void param_kernel(const float* __restrict__ pred,
                             const float* __restrict__ targ,
                             uint32_t* __restrict__ ws) {
    const int b = threadIdx.x;
    if (b >= B) return;
    const uint32_t n = ws[N_OFF + b];
    const uint32_t k0 = (n - 1u) >> 1;
    float med[2], rs[2];
    uint32_t nab[2];
    #pragma unroll
    for (int w = 0; w < 2; w++) {
        float m = ((const float*)(ws + SH_OFF))[w * B + b];
        uint32_t k3 = ws[K_OFF + w * B + b];
        uint32_t e = ws[EQ_OFF + w * B + b];
        float SBv = ((const float*)(ws + SB_OFF))[w * B + b];
        float ST = ((const float*)(ws + TSUM_OFF))[w * B + b];
        uint32_t CB = k0 - k3;                    // count strictly below median
        uint32_t na = n - CB - e;                 // count strictly above
        float Sab = ST - SBv - (float)e * m;      // sum of values above median
        // sum |x - med| = (S_above - n_above*med) + (CB*med - S_below)
        float absdev = (Sab - (float)na * m) + ((float)CB * m - SBv);
        float scale = absdev / (float)n;
        med[w] = m; nab[w] = na;
        rs[w] = 1.f / scale;
        ((float*)(ws + RS_OFF))[w * B + b] = rs[w];
    }
    uint32_t c2 = nab[1];                         // count(targ > st)
    ws[C2_OFF + b] = c2;
    uint32_t mi = (uint32_t)NPX - c2 + (uint32_t)TRIM_IDX;
    if (mi > (uint32_t)(NPX - 1)) mi = NPX - 1;
    float p = pred[(size_t)b * NPX + mi];
    float t = targ[(size_t)b * NPX + mi];
    float pn = (p - med[0]) * rs[0], tn = (t - med[1]) * rs[1];
    ((float*)(ws + THR_OFF))[b] = (tn > 0.f) ? fabsf(pn - tn) : 0.f;
}

// ---------------- fused loss: one wave per row, float4 loads, shuffles ----------------
__global__ void __launch_bounds__(256) loss_kernel(const float* __restrict__ pred,
                                                   const float* __restrict__ targ,
                                                   uint32_t* __restrict__ ws) {
    const int wid = (blockIdx.x << 2) + (threadIdx.x >> 6);   // global wave = row
    const int b = wid / H;
    const int i = wid - b * H;
    const int l = threadIdx.x & 63;
    const float sp = ((const float*)(ws + SH_OFF))[b];
    const float st = ((const float*)(ws + SH_OFF))[B + b];
    const float rp = ((const float*)(ws + RS_OFF))[b];
    const float rt = ((const float*)(ws + RS_OFF))[B + b];
    const float thr = ((const float*)(ws + THR_OFF))[b];
    const float* pb = pred + (size_t)b * NPX;
    const float* tb = targ + (size_t)b * NPX;
    const int ro = i * W + l * 8;

    float t[8], p[8], pn[8];
    bool m[8];
    {
        float4 a = *(const float4*)(tb + ro);
        float4 c = *(const float4*)(tb + ro + 4);
        t[0]=a.x; t[1]=a.y; t[2]=a.z; t[3]=a.w; t[4]=c.x; t[5]=c.y; t[6]=c.z; t[7]=c.w;
        float4 d = *(const float4*)(pb + ro);
        float4 e = *(const float4*)(pb + ro + 4);
        p[0]=d.x; p[1]=d.y; p[2]=d.z; p[3]=d.w; p[4]=e.x; p[5]=e.y; p[6]=e.z; p[7]=e.w;
    }
    #pragma unroll
    for (int k = 0; k < 8; k++) { pn[k] = (p[k] - sp) * rp; m[k] = t[k] > st; }

    float tl = 0.f, gl0 = 0.f, gl1 = 0.f, gl2 = 0.f, gl3 = 0.f;
    uint32_t mc = 0;

    #pragma unroll
    for (int k = 0; k < 8; k++) {
        if (m[k]) {
            float tn = (t[k] - st) * rt;
            float r = fabsf(pn[k] - tn);
            if (r <= thr) tl += r;
        }
    }
    // cross-lane left neighbors (cols l*8-1, -2, -4, -8)
    float t7p = __shfl_up(t[7], 1), pn7p = __shfl_up(pn[7], 1);
    float t6p = __shfl_up(t[6], 1), pn6p = __shfl_up(pn[6], 1);
    float t4p = __shfl_up(t[4], 1), pn4p = __shfl_up(pn[4], 1);
    float t0p = __shfl_up(t[0], 1), pn0p = __shfl_up(pn[0], 1);

    // scale 0 horizontal
    if (l > 0 && m[0] && t7p > st) gl0 += fabsf(pn[0] - pn7p);
    #pragma unroll
    for (int k = 1; k < 8; k++) if (m[k] && m[k - 1]) gl0 += fabsf(pn[k] - pn[k - 1]);
    // scale 0 vertical
    if (i > 0) {
        float4 a = *(const float4*)(tb + ro - W);
        float4 c = *(const float4*)(tb + ro - W + 4);
        float4 d = *(const float4*)(pb + ro - W);
        float4 e = *(const float4*)(pb + ro - W + 4);
        float tu[8] = {a.x,a.y,a.z,a.w,c.x,c.y,c.z,c.w};
        float pu[8] = {d.x,d.y,d.z,d.w,e.x,e.y,e.z,e.w};
        #pragma unroll
        for (int k = 0; k < 8; k++)
            if (m[k] && tu[k] > st) gl0 += fabsf(pn[k] - (pu[k] - sp) * rp);
    }
    if ((i & 1) == 0) {   // scale 1 (step 2)
        mc += (uint32_t)m[0] + m[2] + m[4] + m[6];
        if (l > 0 && m[0] && t6p > st) gl1 += fabsf(pn[0] - pn6p);
        if (m[2] && m[0]) gl1 += fabsf(pn[2] - pn[0]);
        if (m[4] && m[2]) gl1 += fabsf(pn[4] - pn[2]);
        if (m[6] && m[4]) gl1 += fabsf(pn[6] - pn[4]);
        if (i >= 2) {
            float4 a = *(const float4*)(tb + ro - 2 * W);
            float4 c = *(const float4*)(tb + ro - 2 * W + 4);
            float4 d = *(const float4*)(pb + ro - 2 * W);
            float4 e = *(const float4*)(pb + ro - 2 * W + 4);
            if (m[0] && a.x > st) gl1 += fabsf(pn[0] - (d.x - sp) * rp);
            if (m[2] && a.z > st) gl1 += fabsf(pn[2] - (d.z - sp) * rp);
            if (m[4] && c.x > st) gl1 += fabsf(pn[4] - (e.x - sp) * rp);
            if (m[6] && c.z > st) gl1 += fabsf(pn[6] - (e.z - sp) * rp);
        }
        if ((i & 3) == 0) {   // scale 2 (step 4)
            mc += ((uint32_t)m[0] + m[4]) << 10;
            if (l > 0 && m[0] && t4p > st) gl2 += fabsf(pn[0] - pn4p);
            if (m[4] && m[0]) gl2 += fabsf(pn[4] - pn[0]);
            if (i >= 4) {
                float tu0 = tb[ro - 4 * W], tu4 = tb[ro - 4 * W + 4];
                float pu0 = pb[ro - 4 * W], pu4 = pb[ro - 4 * W + 4];
                if (m[0] && tu0 > st) gl2 += fabsf(pn[0] - (pu0 - sp) * rp);
                if (m[4] && tu4 > st) gl2 += fabsf(pn[4] - (pu4 - sp) * rp);
            }
            if ((i & 7) == 0) {   // scale 3 (step 8)
                mc += ((uint32_t)m[0]) << 20;
                if (l > 0 && m[0] && t0p > st) gl3 += fabsf(pn[0] - pn0p);
                if (i >= 8) {
                    float tu0 = tb[ro - 8 * W], pu0 = pb[ro - 8 * W];
                    if (m[0] && tu0 > st) gl3 += fabsf(pn[0] - (pu0 - sp) * rp);
                }
            }
        }
    }
    for (int off = 32; off; off >>= 1) {
        tl  += __shfl_down(tl, off, 64);
        gl0 += __shfl_down(gl0, off, 64);
        gl1 += __shfl_down(gl1, off, 64);
        gl2 += __shfl_down(gl2, off, 64);
        gl3 += __shfl_down(gl3, off, 64);
        mc  += __shfl_down(mc, off, 64);
    }
    if (l == 0) {
        float* gs = (float*)(ws + GS_OFF);
        atomicAdd(((float*)(ws + TS_OFF)) + b, tl);
        atomicAdd(gs + b, gl0);
        if ((i & 1) == 0) {
            atomicAdd(gs + B + b, gl1);
            atomicAdd(ws + MS_OFF + b, mc & 1023u);
            if ((i & 3) == 0) {
                atomicAdd(gs + 2 * B + b, gl2);
                atomicAdd(ws + MS_OFF + B + b, (mc >> 10) & 1023u);
                if ((i & 7) == 0) {
                    atomicAdd(gs + 3 * B + b, gl3);
                    atomicAdd(ws + MS_OFF + 2 * B + b, (mc >> 20) & 1023u);
                }
            }
        }
    }
}

// ---------------- finalize ----------------
__global__ void finalize_kernel(const uint32_t* __restrict__ ws, float* __restrict__ out) {
    const int b = threadIdx.x;
    float v = 0.f;
    if (b < B) {
        float c2 = (float)ws[C2_OFF + b];
        const float* tsum = (const float*)(ws + TS_OFF);
        const float* gsum = (const float*)(ws + GS_OFF);
        float tm = (c2 > 0.f) ? tsum[b] / (2.f * c2) : 0.f;
        float g = (c2 > 0.f) ? gsum[b] / c2 : 0.f;
        for (int z = 0; z < 3; z++) {
            float ms = (float)ws[MS_OFF + z * B + b];
            g += (ms > 0.f) ? gsum[(1 + z) * B + b] / ms : 0.f;
        }
        v = tm + 0.5f * g;
    }
    for (int off = 32; off; off >>= 1) v += __shfl_down(v, off, 64);
    if (b == 0) out[0] = v * (1.f / 64.f);
}

extern "C" void kernel_launch(void* const* d_in, const int* in_sizes, int n_in,
                              void* d_out, int out_size, void* d_ws, size_t ws_size,
                              hipStream_t stream) {
    const float* pred = (const float*)d_in[0];
    const float* targ = (const float*)d_in[1];
    float* out = (float*)d_out;
    uint32_t* ws = (uint32_t*)d_ws;

    hipMemsetAsync(ws, 0, (size_t)ZERO_U32 * 4, stream);

    dim3 hb(256), hg(8, B);
    hist1_kernel<<<hg, hb, 0, stream>>>(pred, targ, ws);
    select_kernel<1><<<dim3(B, 2), 256, 0, stream>>>(ws);

    hipMemsetAsync(ws, 0, (size_t)HIST_U32 * 4, stream);
    hist2_kernel<<<hg, hb, 0, stream>>>(pred, targ, ws);
    select_kernel<2><<<dim3(B, 2), 256, 0, stream>>>(ws);

    hipMemsetAsync(ws, 0, (size_t)HIST_U32 * 4, stream);
    hist3_kernel<<<hg, hb, 0, stream>>>(pred, targ, ws);
    select3_kernel<<<dim3(B, 2), 256, 0, stream>>>(ws);

    param_kernel<<<1, 64, 0, stream>>>(pred, targ, ws);
    loss_kernel<<<dim3((B * H) / 4), 256, 0, stream>>>(pred, targ, ws);
    finalize_kernel<<<1, 64, 0, stream>>>(ws, out);
}